// Round 4
// baseline (1207.244 us; speedup 1.0000x reference)
//
#include <hip/hip_runtime.h>
#include <hip/hip_bf16.h>

// Problem constants (StaticRecurrentEntNet): B=256,S=32,L=32,D=256,E=64,VOCAB=50000
#define Bb 256
#define Ss 32
#define Ll 32
#define Dd 256
#define Ee 64

typedef __attribute__((ext_vector_type(8))) short short8v;
typedef __attribute__((ext_vector_type(4))) float float4v;

static __device__ __forceinline__ unsigned short f2bf(float f) {
    unsigned int x = __float_as_uint(f);
    return (unsigned short)((x + 0x7fffu + ((x >> 16) & 1u)) >> 16);   // RNE
}
static __device__ __forceinline__ unsigned int pk2(float a, float b) {
    return (unsigned int)f2bf(a) | ((unsigned int)f2bf(b) << 16);
}

// ---------------- Kernel A: enc[bs][d] = sum_l emb[tok[bs][l]][d]*mask[bs][l]; active[bs]
__global__ void k_enc(const int* __restrict__ tok, const float* __restrict__ mask,
                      const float* __restrict__ emb, float* __restrict__ enc,
                      int* __restrict__ act) {
    int bs = blockIdx.x;            // 0..B*S-1
    int d  = threadIdx.x;           // 0..255
    const int*   t = tok  + (long)bs * Ll;
    const float* m = mask + (long)bs * Ll;
    float acc = 0.f;
    #pragma unroll 4
    for (int l = 0; l < Ll; ++l) {
        acc += emb[(long)t[l] * Dd + d] * m[l];
    }
    enc[(long)bs * Dd + d] = acc;
    if (d == 0) {
        float s = 0.f;
        for (int l = 0; l < Ll; ++l) s += m[l];
        act[bs] = (s > 0.f) ? 1 : 0;
    }
}

// ---------------- Kernel B: Y[rows][256] = X[rows][256] @ M[256][256]  (fp32)
__global__ void k_rowmat(const float* __restrict__ X, const float* __restrict__ M,
                         float* __restrict__ Y) {
    __shared__ __align__(16) float xs[16 * Dd];
    int tid = threadIdx.x;
    long row0 = (long)blockIdx.x * 16;
    #pragma unroll
    for (int i = 0; i < 16; ++i) xs[i * Dd + tid] = X[(row0 + i) * Dd + tid];
    __syncthreads();
    int cg = tid & 63;   // cols cg*4 .. +3
    int rq = tid >> 6;   // rows rq*4 .. +3
    float acc[4][4];
    #pragma unroll
    for (int r = 0; r < 4; ++r)
        #pragma unroll
        for (int c = 0; c < 4; ++c) acc[r][c] = 0.f;
    for (int d = 0; d < Dd; ++d) {
        float4 mv = *reinterpret_cast<const float4*>(&M[d * Dd + cg * 4]);
        #pragma unroll
        for (int r = 0; r < 4; ++r) {
            float x = xs[(rq * 4 + r) * Dd + d];
            acc[r][0] += x * mv.x; acc[r][1] += x * mv.y;
            acc[r][2] += x * mv.z; acc[r][3] += x * mv.w;
        }
    }
    #pragma unroll
    for (int r = 0; r < 4; ++r) {
        float4 o = make_float4(acc[r][0], acc[r][1], acc[r][2], acc[r][3]);
        *reinterpret_cast<float4*>(&Y[(row0 + rq * 4 + r) * Dd + cg * 4]) = o;
    }
}

// ---------------- Kernel Bgk: gk[bs][e] = dot(enc[bs], keys[b][e]),  b = bs/S
__global__ void k_gk(const float* __restrict__ enc, const float* __restrict__ keys,
                     float* __restrict__ gk) {
    int bs = blockIdx.x;
    int b  = bs >> 5;               // S = 32
    __shared__ __align__(16) float es[Dd];
    int tid = threadIdx.x;
    es[tid] = enc[(long)bs * Dd + tid];
    __syncthreads();
    int e = tid >> 2, q = tid & 3;
    const float* kr = keys + ((long)b * Ee + e) * Dd;
    float p = 0.f;
    #pragma unroll 8
    for (int i = 0; i < 64; ++i) {
        int d = q + 4 * i;
        p += es[d] * kr[d];
    }
    p += __shfl_xor(p, 1);
    p += __shfl_xor(p, 2);
    if (q == 0) gk[(long)bs * Ee + e] = p;
}

// ---------------- Kernel Ut: Utg[c][k] = bf16(U[k][c])  (pre-transpose for A-operand)
__global__ void k_ut(const float* __restrict__ U, unsigned short* __restrict__ Utg) {
    const int c0 = blockIdx.x * 16;
    const int k  = threadIdx.x;      // 0..255
    float v[16];
    #pragma unroll
    for (int i = 0; i < 16; ++i) v[i] = U[k * Dd + c0 + i];
    #pragma unroll
    for (int i = 0; i < 16; ++i) Utg[(c0 + i) * Dd + k] = f2bf(v[i]);
}

// ---------------- Kernel D: 32-step recurrence. Transposed MFMA, zero barriers in loop.
// One block per b; wave w owns entities [w*16, w*16+16). Product computed as
// (h@U)^T = U^T @ h^T: A = U^T from swizzled LDS (128KB, read-only), B = h in regs.
// D-layout: col = lane&15 = entity (pinned per lane!), row = 4q+j = d within tile mi.
// Lane (q,sl): entity e = w*16+sl, holds h[e][d] for d = 16*mi + 4q + j (f32) and
// bf16 B-frags hB[kk][i] = h[e][32kk+8q+i]. D->B repack = 2-round lane butterfly.
__global__ __launch_bounds__(256, 1) void k_scan(
    const float* __restrict__ enc, const int* __restrict__ act,
    const float* __restrict__ gk,  const float* __restrict__ kv,
    const float* __restrict__ eWm, const unsigned short* __restrict__ Utg,
    float* __restrict__ out) {
    __shared__ __align__(16) unsigned short Ut[Dd * Dd];  // [c][k] bf16, swizzled, 128KB

    const int tid = threadIdx.x;
    const int b   = blockIdx.x;
    const int w   = tid >> 6;
    const int l   = tid & 63;
    const int q   = l >> 4;
    const int sl  = l & 15;
    const int e   = w * 16 + sl;

    // ---- stage U^T into LDS with XOR swizzle (conflict-free b128 reads later) ----
    {
        const uint4* g4 = reinterpret_cast<const uint4*>(Utg);
        char* lb = reinterpret_cast<char*>(Ut);
        #pragma unroll
        for (int r = 0; r < 32; ++r) {
            const int u  = tid + 256 * r;          // 16B unit id, 0..8191
            const int c  = u >> 5;                 // row (c) 0..255
            const int kb = (u & 31) << 4;          // byte offset within row
            const uint4 v = g4[u];
            *reinterpret_cast<uint4*>(lb + (((c << 9) + kb) ^ ((c & 7) << 4))) = v;
        }
    }

    // ---- preload kv (loop-invariant), D-layout ----
    float4v kvr[16];
    const float* kvrow = kv + ((long)b * Ee + e) * Dd;
    #pragma unroll
    for (int mi = 0; mi < 16; ++mi) {
        const float4 t = *reinterpret_cast<const float4*>(kvrow + mi * 16 + q * 4);
        kvr[mi] = (float4v){t.x, t.y, t.z, t.w};
    }

    float4v h_d[16];
    #pragma unroll
    for (int mi = 0; mi < 16; ++mi) h_d[mi] = (float4v)0.f;
    uint4 hB[8];
    #pragma unroll
    for (int kk = 0; kk < 8; ++kk) hB[kk] = make_uint4(0u, 0u, 0u, 0u);

    // lane-constant butterfly predicates
    const bool hiq = (q >> 1) != 0;            // keep parity
    const bool par = (((q >> 1) ^ q) & 1) != 0; // round-2 send select
    const int  abase = (sl << 9) + (q << 4);
    const int  swz   = (sl & 7) << 4;

    __syncthreads();   // Ut staged

    for (int s = 0; s < Ss; ++s) {
        const long bs = (long)b * Ss + s;
        const int  a  = act[bs];                    // uniform per block
        const float gk_s = gk[bs * Ee + e];
        const float* erow = enc + bs * Dd;

        // ---- g-dot: dot(es, h[e]) — lane-local partial + 2 shuffles ----
        float gd = 0.f;
        #pragma unroll
        for (int mi = 0; mi < 16; ++mi) {
            const float4 ev = *reinterpret_cast<const float4*>(erow + mi * 16 + q * 4);
            gd += ev.x * h_d[mi][0] + ev.y * h_d[mi][1]
                + ev.z * h_d[mi][2] + ev.w * h_d[mi][3];
        }
        gd += __shfl_xor(gd, 16);
        gd += __shfl_xor(gd, 32);
        const float g = 1.f / (1.f + expf(-(gd + gk_s)));

        // ---- GEMM: acc (D-layout) = U^T @ h^T ; A from LDS, B from registers ----
        float4v acc[16];
        #pragma unroll
        for (int mi = 0; mi < 16; ++mi) acc[mi] = (float4v)0.f;
        const char* lb = reinterpret_cast<const char*>(Ut);
        #pragma unroll
        for (int kk = 0; kk < 8; ++kk) {
            const short8v bv = __builtin_bit_cast(short8v, hB[kk]);
            const int bk = (abase + (kk << 6)) ^ swz;
            #pragma unroll
            for (int mi = 0; mi < 16; ++mi) {
                const short8v av = *reinterpret_cast<const short8v*>(lb + bk + mi * 8192);
                acc[mi] = __builtin_amdgcn_mfma_f32_16x16x32_bf16(av, bv, acc[mi], 0, 0, 0);
            }
        }

        // ---- epilogue (all lane-local): h_t = relu(acc+kv+eW); h_new = h + g*h_t ----
        float ss = 0.f;
        const float* ewrow = eWm + bs * Dd;
        #pragma unroll
        for (int mi = 0; mi < 16; ++mi) {
            const float4 ew = *reinterpret_cast<const float4*>(ewrow + mi * 16 + q * 4);
            const float ewa[4] = {ew.x, ew.y, ew.z, ew.w};
            #pragma unroll
            for (int j = 0; j < 4; ++j) {
                float ht = acc[mi][j] + kvr[mi][j] + ewa[j];
                ht = fmaxf(ht, 0.f);
                const float hn = h_d[mi][j] + g * ht;
                acc[mi][j] = hn;                    // acc := unnormalized h_new
                ss += hn * hn;
            }
        }
        ss += __shfl_xor(ss, 16);
        ss += __shfl_xor(ss, 32);
        const float rn = rsqrtf(fmaxf(ss, 1e-12f));

        if (a) {
            #pragma unroll
            for (int mi = 0; mi < 16; ++mi) {
                #pragma unroll
                for (int j = 0; j < 4; ++j) h_d[mi][j] = acc[mi][j] * rn;
            }
            // ---- rebuild bf16 B-frags: 2-round q-butterfly (xor32 then xor16) ----
            #pragma unroll
            for (int kk = 0; kk < 8; ++kk) {
                const unsigned int P0a = pk2(h_d[2 * kk][0],     h_d[2 * kk][1]);
                const unsigned int P0b = pk2(h_d[2 * kk][2],     h_d[2 * kk][3]);
                const unsigned int P1a = pk2(h_d[2 * kk + 1][0], h_d[2 * kk + 1][1]);
                const unsigned int P1b = pk2(h_d[2 * kk + 1][2], h_d[2 * kk + 1][3]);
                const unsigned int Ka  = hiq ? P1a : P0a, Kb  = hiq ? P1b : P0b;
                const unsigned int S1a = hiq ? P0a : P1a, S1b = hiq ? P0b : P1b;
                const unsigned int R1a = (unsigned int)__shfl_xor((int)S1a, 32);
                const unsigned int R1b = (unsigned int)__shfl_xor((int)S1b, 32);
                const unsigned int S2a = par ? Ka : R1a, S2b = par ? Kb : R1b;
                const unsigned int R2a = (unsigned int)__shfl_xor((int)S2a, 16);
                const unsigned int R2b = (unsigned int)__shfl_xor((int)S2b, 16);
                const unsigned int LOa = (q == 0) ? Ka : (q == 2) ? R1a : R2a;
                const unsigned int LOb = (q == 0) ? Kb : (q == 2) ? R1b : R2b;
                const unsigned int HIa = (q == 3) ? Ka : (q == 1) ? R1a : R2a;
                const unsigned int HIb = (q == 3) ? Kb : (q == 1) ? R1b : R2b;
                hB[kk] = make_uint4(LOa, LOb, HIa, HIb);
            }
        }
    }

    // ---- write back h (fp32) ----
    float* orow = out + ((long)b * Ee + e) * Dd;
    #pragma unroll
    for (int mi = 0; mi < 16; ++mi) {
        *reinterpret_cast<float4v*>(orow + mi * 16 + q * 4) = h_d[mi];
    }
}

extern "C" void kernel_launch(void* const* d_in, const int* in_sizes, int n_in,
                              void* d_out, int out_size, void* d_ws, size_t ws_size,
                              hipStream_t stream) {
    const int*   tok  = (const int*)d_in[0];    // (B,S,L) int32
    const float* mask = (const float*)d_in[1];  // (B,S,L) f32
    const float* keys = (const float*)d_in[2];  // (B,E,D) f32
    const float* emb  = (const float*)d_in[3];  // (VOCAB,D) f32
    const float* U    = (const float*)d_in[4];  // (D,D)
    const float* V    = (const float*)d_in[5];  // (D,D)
    const float* W    = (const float*)d_in[6];  // (D,D)
    float* out = (float*)d_out;

    // workspace layout (floats)
    float* enc = (float*)d_ws;                    // B*S*D      = 2,097,152
    float* kv  = enc + (long)Bb * Ss * Dd;        // B*E*D      = 4,194,304
    float* eW  = kv  + (long)Bb * Ee * Dd;        // B*S*D      = 2,097,152
    float* gkv = eW  + (long)Bb * Ss * Dd;        // B*S*E      =   524,288
    int*   act = (int*)(gkv + (long)Bb * Ss * Ee);// B*S        =     8,192 ints
    unsigned short* Utg = (unsigned short*)(act + Bb * Ss);  // D*D bf16 = 131,072 B

    k_enc<<<Bb * Ss, Dd, 0, stream>>>(tok, mask, emb, enc, act);
    k_rowmat<<<(Bb * Ee) / 16, 256, 0, stream>>>(keys, V, kv);   // kv = keys @ V
    k_rowmat<<<(Bb * Ss) / 16, 256, 0, stream>>>(enc, W, eW);    // eW = enc @ W
    k_gk<<<Bb * Ss, 256, 0, stream>>>(enc, keys, gkv);           // gk = dot(enc, keys)
    k_ut<<<Dd / 16, Dd, 0, stream>>>(U, Utg);                    // Utg = bf16(U^T)
    k_scan<<<Bb, 256, 0, stream>>>(enc, act, gkv, kv, eW, Utg, out);
}

// Round 5
// 607.709 us; speedup vs baseline: 1.9866x; 1.9866x over previous
//
#include <hip/hip_runtime.h>
#include <hip/hip_bf16.h>

// Problem constants (StaticRecurrentEntNet): B=256,S=32,L=32,D=256,E=64,VOCAB=50000
#define Bb 256
#define Ss 32
#define Ll 32
#define Dd 256
#define Ee 64

typedef __attribute__((ext_vector_type(8))) short short8v;
typedef __attribute__((ext_vector_type(4))) float float4v;

static __device__ __forceinline__ unsigned short f2bf(float f) {
    unsigned int x = __float_as_uint(f);
    return (unsigned short)((x + 0x7fffu + ((x >> 16) & 1u)) >> 16);   // RNE
}
static __device__ __forceinline__ unsigned int pk2(float a, float b) {
    return (unsigned int)f2bf(a) | ((unsigned int)f2bf(b) << 16);
}

// ---------------- Kernel A: enc[bs][d] = sum_l emb[tok[bs][l]][d]*mask[bs][l]; active[bs]
__global__ void k_enc(const int* __restrict__ tok, const float* __restrict__ mask,
                      const float* __restrict__ emb, float* __restrict__ enc,
                      int* __restrict__ act) {
    int bs = blockIdx.x;            // 0..B*S-1
    int d  = threadIdx.x;           // 0..255
    const int*   t = tok  + (long)bs * Ll;
    const float* m = mask + (long)bs * Ll;
    float acc = 0.f;
    #pragma unroll 4
    for (int l = 0; l < Ll; ++l) {
        acc += emb[(long)t[l] * Dd + d] * m[l];
    }
    enc[(long)bs * Dd + d] = acc;
    if (d == 0) {
        float s = 0.f;
        for (int l = 0; l < Ll; ++l) s += m[l];
        act[bs] = (s > 0.f) ? 1 : 0;
    }
}

// ---------------- Kernel B: Y[rows][256] = X[rows][256] @ M[256][256]  (fp32)
__global__ void k_rowmat(const float* __restrict__ X, const float* __restrict__ M,
                         float* __restrict__ Y) {
    __shared__ __align__(16) float xs[16 * Dd];
    int tid = threadIdx.x;
    long row0 = (long)blockIdx.x * 16;
    #pragma unroll
    for (int i = 0; i < 16; ++i) xs[i * Dd + tid] = X[(row0 + i) * Dd + tid];
    __syncthreads();
    int cg = tid & 63;   // cols cg*4 .. +3
    int rq = tid >> 6;   // rows rq*4 .. +3
    float acc[4][4];
    #pragma unroll
    for (int r = 0; r < 4; ++r)
        #pragma unroll
        for (int c = 0; c < 4; ++c) acc[r][c] = 0.f;
    for (int d = 0; d < Dd; ++d) {
        float4 mv = *reinterpret_cast<const float4*>(&M[d * Dd + cg * 4]);
        #pragma unroll
        for (int r = 0; r < 4; ++r) {
            float x = xs[(rq * 4 + r) * Dd + d];
            acc[r][0] += x * mv.x; acc[r][1] += x * mv.y;
            acc[r][2] += x * mv.z; acc[r][3] += x * mv.w;
        }
    }
    #pragma unroll
    for (int r = 0; r < 4; ++r) {
        float4 o = make_float4(acc[r][0], acc[r][1], acc[r][2], acc[r][3]);
        *reinterpret_cast<float4*>(&Y[(row0 + rq * 4 + r) * Dd + cg * 4]) = o;
    }
}

// ---------------- Kernel Bgk: gk[bs][e] = dot(enc[bs], keys[b][e]),  b = bs/S
__global__ void k_gk(const float* __restrict__ enc, const float* __restrict__ keys,
                     float* __restrict__ gk) {
    int bs = blockIdx.x;
    int b  = bs >> 5;               // S = 32
    __shared__ __align__(16) float es[Dd];
    int tid = threadIdx.x;
    es[tid] = enc[(long)bs * Dd + tid];
    __syncthreads();
    int e = tid >> 2, q = tid & 3;
    const float* kr = keys + ((long)b * Ee + e) * Dd;
    float p = 0.f;
    #pragma unroll 8
    for (int i = 0; i < 64; ++i) {
        int d = q + 4 * i;
        p += es[d] * kr[d];
    }
    p += __shfl_xor(p, 1);
    p += __shfl_xor(p, 2);
    if (q == 0) gk[(long)bs * Ee + e] = p;
}

// ---------------- Kernel Ut: Utg[c][k] = bf16(U[k][c])  (pre-transpose for A-operand)
__global__ void k_ut(const float* __restrict__ U, unsigned short* __restrict__ Utg) {
    const int c0 = blockIdx.x * 16;
    const int k  = threadIdx.x;      // 0..255
    float v[16];
    #pragma unroll
    for (int i = 0; i < 16; ++i) v[i] = U[k * Dd + c0 + i];
    #pragma unroll
    for (int i = 0; i < 16; ++i) Utg[(c0 + i) * Dd + k] = f2bf(v[i]);
}

// ---------------- Kernel D: 32-step recurrence. Transposed MFMA, zero barriers in loop.
// One block per b; wave w owns entities [w*16, w*16+16). Product computed as
// (h@U)^T = U^T @ h^T: A = U^T from swizzled LDS (128KB, read-only), B = h in regs.
// D-layout: col = lane&15 = entity (pinned per lane!), row = 4q+j = d within tile mi.
// Register-pressure discipline (round-4 spilled at ~1.5GB scratch fetch):
//   - no resident kv (reloaded from L2 each step)
//   - GEMM+epilogue split in two mi-halves so only acc[8] is live
__global__ __launch_bounds__(256, 1) void k_scan(
    const float* __restrict__ enc, const int* __restrict__ act,
    const float* __restrict__ gk,  const float* __restrict__ kv,
    const float* __restrict__ eWm, const unsigned short* __restrict__ Utg,
    float* __restrict__ out) {
    __shared__ __align__(16) unsigned short Ut[Dd * Dd];  // [c][k] bf16, swizzled, 128KB

    const int tid = threadIdx.x;
    const int b   = blockIdx.x;
    const int w   = tid >> 6;
    const int l   = tid & 63;
    const int q   = l >> 4;
    const int sl  = l & 15;
    const int e   = w * 16 + sl;

    // ---- stage U^T into LDS with XOR swizzle (conflict-free b128 reads later) ----
    {
        const uint4* g4 = reinterpret_cast<const uint4*>(Utg);
        char* lb = reinterpret_cast<char*>(Ut);
        #pragma unroll
        for (int r = 0; r < 32; ++r) {
            const int u  = tid + 256 * r;          // 16B unit id, 0..8191
            const int c  = u >> 5;                 // row (c) 0..255
            const int kb = (u & 31) << 4;          // byte offset within row
            const uint4 v = g4[u];
            *reinterpret_cast<uint4*>(lb + (((c << 9) + kb) ^ ((c & 7) << 4))) = v;
        }
    }

    float4v h_d[16];
    #pragma unroll
    for (int mi = 0; mi < 16; ++mi) h_d[mi] = (float4v)0.f;
    uint4 hB[8];
    #pragma unroll
    for (int kk = 0; kk < 8; ++kk) hB[kk] = make_uint4(0u, 0u, 0u, 0u);

    // lane-constant butterfly predicates
    const bool hiq = (q >> 1) != 0;             // keep parity
    const bool par = (((q >> 1) ^ q) & 1) != 0; // round-2 send select
    const int  abase = (sl << 9) + (q << 4);
    const int  swz   = (sl & 7) << 4;
    const float* kvrow = kv + ((long)b * Ee + e) * Dd;

    __syncthreads();   // Ut staged

    for (int s = 0; s < Ss; ++s) {
        const long bs = (long)b * Ss + s;
        const int  a  = act[bs];                    // uniform per block
        if (a) {
            const float gk_s = gk[bs * Ee + e];
            const float* erow = enc + bs * Dd;

            // ---- g-dot: dot(es, h[e]) — lane-local partial + 2 shuffles ----
            float gd = 0.f;
            #pragma unroll
            for (int mi = 0; mi < 16; ++mi) {
                const float4 ev = *reinterpret_cast<const float4*>(erow + mi * 16 + q * 4);
                gd += ev.x * h_d[mi][0] + ev.y * h_d[mi][1]
                    + ev.z * h_d[mi][2] + ev.w * h_d[mi][3];
            }
            gd += __shfl_xor(gd, 16);
            gd += __shfl_xor(gd, 32);
            const float g = 1.f / (1.f + expf(-(gd + gk_s)));

            // ---- GEMM + epilogue in two mi-halves (acc[8] live, not acc[16]) ----
            const char* lb = reinterpret_cast<const char*>(Ut);
            const float* ewrow = eWm + bs * Dd;
            float ss = 0.f;
            #pragma unroll
            for (int hf = 0; hf < 2; ++hf) {
                float4v acc[8];
                #pragma unroll
                for (int m8 = 0; m8 < 8; ++m8) acc[m8] = (float4v)0.f;
                #pragma unroll
                for (int kk = 0; kk < 8; ++kk) {
                    const short8v bv = __builtin_bit_cast(short8v, hB[kk]);
                    const int bk = (abase + (kk << 6)) ^ swz;
                    #pragma unroll
                    for (int m8 = 0; m8 < 8; ++m8) {
                        const int mi = hf * 8 + m8;
                        const short8v av = *reinterpret_cast<const short8v*>(
                            lb + bk + mi * 8192);
                        acc[m8] = __builtin_amdgcn_mfma_f32_16x16x32_bf16(
                            av, bv, acc[m8], 0, 0, 0);
                    }
                }
                // epilogue half: h_t = relu(acc+kv+eW); h_d := h + g*h_t (unnormalized)
                #pragma unroll
                for (int m8 = 0; m8 < 8; ++m8) {
                    const int mi = hf * 8 + m8;
                    const float4 ew = *reinterpret_cast<const float4*>(
                        ewrow + mi * 16 + q * 4);
                    const float4 kvv = *reinterpret_cast<const float4*>(
                        kvrow + mi * 16 + q * 4);
                    const float ewa[4] = {ew.x, ew.y, ew.z, ew.w};
                    const float kva[4] = {kvv.x, kvv.y, kvv.z, kvv.w};
                    #pragma unroll
                    for (int j = 0; j < 4; ++j) {
                        float ht = acc[m8][j] + kva[j] + ewa[j];
                        ht = fmaxf(ht, 0.f);
                        const float hn = h_d[mi][j] + g * ht;
                        h_d[mi][j] = hn;
                        ss += hn * hn;
                    }
                }
            }
            ss += __shfl_xor(ss, 16);
            ss += __shfl_xor(ss, 32);
            const float rn = rsqrtf(fmaxf(ss, 1e-12f));

            #pragma unroll
            for (int mi = 0; mi < 16; ++mi) {
                #pragma unroll
                for (int j = 0; j < 4; ++j) h_d[mi][j] *= rn;
            }
            // ---- rebuild bf16 B-frags: 2-round q-butterfly (xor32 then xor16) ----
            #pragma unroll
            for (int kk = 0; kk < 8; ++kk) {
                const unsigned int P0a = pk2(h_d[2 * kk][0],     h_d[2 * kk][1]);
                const unsigned int P0b = pk2(h_d[2 * kk][2],     h_d[2 * kk][3]);
                const unsigned int P1a = pk2(h_d[2 * kk + 1][0], h_d[2 * kk + 1][1]);
                const unsigned int P1b = pk2(h_d[2 * kk + 1][2], h_d[2 * kk + 1][3]);
                const unsigned int Ka  = hiq ? P1a : P0a, Kb  = hiq ? P1b : P0b;
                const unsigned int S1a = hiq ? P0a : P1a, S1b = hiq ? P0b : P1b;
                const unsigned int R1a = (unsigned int)__shfl_xor((int)S1a, 32);
                const unsigned int R1b = (unsigned int)__shfl_xor((int)S1b, 32);
                const unsigned int S2a = par ? Ka : R1a, S2b = par ? Kb : R1b;
                const unsigned int R2a = (unsigned int)__shfl_xor((int)S2a, 16);
                const unsigned int R2b = (unsigned int)__shfl_xor((int)S2b, 16);
                const unsigned int LOa = (q == 0) ? Ka : (q == 2) ? R1a : R2a;
                const unsigned int LOb = (q == 0) ? Kb : (q == 2) ? R1b : R2b;
                const unsigned int HIa = (q == 3) ? Ka : (q == 1) ? R1a : R2a;
                const unsigned int HIb = (q == 3) ? Kb : (q == 1) ? R1b : R2b;
                hB[kk] = make_uint4(LOa, LOb, HIa, HIb);
            }
        }
    }

    // ---- write back h (fp32) ----
    float* orow = out + ((long)b * Ee + e) * Dd;
    #pragma unroll
    for (int mi = 0; mi < 16; ++mi) {
        *reinterpret_cast<float4v*>(orow + mi * 16 + q * 4) = h_d[mi];
    }
}

extern "C" void kernel_launch(void* const* d_in, const int* in_sizes, int n_in,
                              void* d_out, int out_size, void* d_ws, size_t ws_size,
                              hipStream_t stream) {
    const int*   tok  = (const int*)d_in[0];    // (B,S,L) int32
    const float* mask = (const float*)d_in[1];  // (B,S,L) f32
    const float* keys = (const float*)d_in[2];  // (B,E,D) f32
    const float* emb  = (const float*)d_in[3];  // (VOCAB,D) f32
    const float* U    = (const float*)d_in[4];  // (D,D)
    const float* V    = (const float*)d_in[5];  // (D,D)
    const float* W    = (const float*)d_in[6];  // (D,D)
    float* out = (float*)d_out;

    // workspace layout (floats)
    float* enc = (float*)d_ws;                    // B*S*D      = 2,097,152
    float* kv  = enc + (long)Bb * Ss * Dd;        // B*E*D      = 4,194,304
    float* eW  = kv  + (long)Bb * Ee * Dd;        // B*S*D      = 2,097,152
    float* gkv = eW  + (long)Bb * Ss * Dd;        // B*S*E      =   524,288
    int*   act = (int*)(gkv + (long)Bb * Ss * Ee);// B*S        =     8,192 ints
    unsigned short* Utg = (unsigned short*)(act + Bb * Ss);  // D*D bf16 = 131,072 B

    k_enc<<<Bb * Ss, Dd, 0, stream>>>(tok, mask, emb, enc, act);
    k_rowmat<<<(Bb * Ee) / 16, 256, 0, stream>>>(keys, V, kv);   // kv = keys @ V
    k_rowmat<<<(Bb * Ss) / 16, 256, 0, stream>>>(enc, W, eW);    // eW = enc @ W
    k_gk<<<Bb * Ss, 256, 0, stream>>>(enc, keys, gkv);           // gk = dot(enc, keys)
    k_ut<<<Dd / 16, Dd, 0, stream>>>(U, Utg);                    // Utg = bf16(U^T)
    k_scan<<<Bb, 256, 0, stream>>>(enc, act, gkv, kv, eW, Utg, out);
}

// Round 6
// 493.168 us; speedup vs baseline: 2.4479x; 1.2323x over previous
//
#include <hip/hip_runtime.h>
#include <hip/hip_bf16.h>

// Problem constants (StaticRecurrentEntNet): B=256,S=32,L=32,D=256,E=64,VOCAB=50000
#define Bb 256
#define Ss 32
#define Ll 32
#define Dd 256
#define Ee 64

typedef __attribute__((ext_vector_type(8))) short short8v;
typedef __attribute__((ext_vector_type(4))) float float4v;

static __device__ __forceinline__ unsigned short f2bf(float f) {
    unsigned int x = __float_as_uint(f);
    return (unsigned short)((x + 0x7fffu + ((x >> 16) & 1u)) >> 16);   // RNE
}
static __device__ __forceinline__ unsigned int pk2(float a, float b) {
    return (unsigned int)f2bf(a) | ((unsigned int)f2bf(b) << 16);
}

// ---------------- Kernel A: enc[bs][d] = sum_l emb[tok[bs][l]][d]*mask[bs][l]; active[bs]
__global__ void k_enc(const int* __restrict__ tok, const float* __restrict__ mask,
                      const float* __restrict__ emb, float* __restrict__ enc,
                      int* __restrict__ act) {
    int bs = blockIdx.x;            // 0..B*S-1
    int d  = threadIdx.x;           // 0..255
    const int*   t = tok  + (long)bs * Ll;
    const float* m = mask + (long)bs * Ll;
    float acc = 0.f;
    #pragma unroll 4
    for (int l = 0; l < Ll; ++l) {
        acc += emb[(long)t[l] * Dd + d] * m[l];
    }
    enc[(long)bs * Dd + d] = acc;
    if (d == 0) {
        float s = 0.f;
        for (int l = 0; l < Ll; ++l) s += m[l];
        act[bs] = (s > 0.f) ? 1 : 0;
    }
}

// ---------------- Kernel B: Y[rows][256] = X[rows][256] @ M[256][256]  (fp32)
// 64 rows per block (4x fewer M re-reads than 16-row tile). Same per-element
// FMA order as before -> bitwise-identical results.
__global__ void k_rowmat(const float* __restrict__ X, const float* __restrict__ M,
                         float* __restrict__ Y) {
    __shared__ __align__(16) float xs[64 * Dd];   // 64KB
    int tid = threadIdx.x;
    long row0 = (long)blockIdx.x * 64;
    {
        const float4* xg = reinterpret_cast<const float4*>(X + row0 * Dd);
        float4* xs4 = reinterpret_cast<float4*>(xs);
        #pragma unroll
        for (int i = 0; i < 16; ++i) xs4[tid + 256 * i] = xg[tid + 256 * i];
    }
    __syncthreads();
    int cg = tid & 63;   // cols cg*4 .. +3
    int rq = tid >> 6;   // rows rq*16 .. +15
    float acc[16][4];
    #pragma unroll
    for (int r = 0; r < 16; ++r)
        #pragma unroll
        for (int c = 0; c < 4; ++c) acc[r][c] = 0.f;
    for (int d = 0; d < Dd; ++d) {
        float4 mv = *reinterpret_cast<const float4*>(&M[d * Dd + cg * 4]);
        #pragma unroll
        for (int r = 0; r < 16; ++r) {
            float x = xs[(rq * 16 + r) * Dd + d];
            acc[r][0] += x * mv.x; acc[r][1] += x * mv.y;
            acc[r][2] += x * mv.z; acc[r][3] += x * mv.w;
        }
    }
    #pragma unroll
    for (int r = 0; r < 16; ++r) {
        float4 o = make_float4(acc[r][0], acc[r][1], acc[r][2], acc[r][3]);
        *reinterpret_cast<float4*>(&Y[(row0 + rq * 16 + r) * Dd + cg * 4]) = o;
    }
}

// ---------------- Kernel Bgk: gk[bs][e] = dot(enc[bs], keys[b][e]),  b = bs/S
__global__ void k_gk(const float* __restrict__ enc, const float* __restrict__ keys,
                     float* __restrict__ gk) {
    int bs = blockIdx.x;
    int b  = bs >> 5;               // S = 32
    __shared__ __align__(16) float es[Dd];
    int tid = threadIdx.x;
    es[tid] = enc[(long)bs * Dd + tid];
    __syncthreads();
    int e = tid >> 2, q = tid & 3;
    const float* kr = keys + ((long)b * Ee + e) * Dd;
    float p = 0.f;
    #pragma unroll 8
    for (int i = 0; i < 64; ++i) {
        int d = q + 4 * i;
        p += es[d] * kr[d];
    }
    p += __shfl_xor(p, 1);
    p += __shfl_xor(p, 2);
    if (q == 0) gk[(long)bs * Ee + e] = p;
}

// ---------------- Kernel Ut: Utg[c][k] = bf16(U[k][c])  (pre-transpose for A-operand)
__global__ void k_ut(const float* __restrict__ U, unsigned short* __restrict__ Utg) {
    const int c0 = blockIdx.x * 16;
    const int k  = threadIdx.x;      // 0..255
    float v[16];
    #pragma unroll
    for (int i = 0; i < 16; ++i) v[i] = U[k * Dd + c0 + i];
    #pragma unroll
    for (int i = 0; i < 16; ++i) Utg[(c0 + i) * Dd + k] = f2bf(v[i]);
}

// ---------------- Kernel D: 32-step recurrence. Transposed MFMA, zero barriers in loop.
// One block per b; wave w owns entities [w*16, w*16+16). Product computed as
// (h@U)^T = U^T @ h^T: A = U^T from swizzled LDS (128KB, read-only), B = h in regs.
// D-layout: col = lane&15 = entity (pinned per lane!), row = 4q+j = d within tile mi.
// Round-6 fix: A-fragments explicitly double-buffered (2x8 frags = 64 VGPR) so
// ds_read latency pipelines under MFMAs (round-5 had VGPR=136 -> serialized
// read->waitcnt->MFMA at ~120cyc each). Reduction chains split 4-way. act via
// one-time ballot mask.
__global__ __launch_bounds__(256, 1) void k_scan(
    const float* __restrict__ enc, const int* __restrict__ act,
    const float* __restrict__ gk,  const float* __restrict__ kv,
    const float* __restrict__ eWm, const unsigned short* __restrict__ Utg,
    float* __restrict__ out) {
    __shared__ __align__(16) unsigned short Ut[Dd * Dd];  // [c][k] bf16, swizzled, 128KB

    const int tid = threadIdx.x;
    const int b   = blockIdx.x;
    const int w   = tid >> 6;
    const int l   = tid & 63;
    const int q   = l >> 4;
    const int sl  = l & 15;
    const int e   = w * 16 + sl;

    // ---- stage U^T into LDS with XOR swizzle (conflict-free b128 reads later) ----
    {
        const uint4* g4 = reinterpret_cast<const uint4*>(Utg);
        char* lb = reinterpret_cast<char*>(Ut);
        #pragma unroll
        for (int r = 0; r < 32; ++r) {
            const int u  = tid + 256 * r;          // 16B unit id, 0..8191
            const int c  = u >> 5;                 // row (c) 0..255
            const int kb = (u & 31) << 4;          // byte offset within row
            const uint4 v = g4[u];
            *reinterpret_cast<uint4*>(lb + (((c << 9) + kb) ^ ((c & 7) << 4))) = v;
        }
    }

    // ---- one-time active-mask (removes a ~200cyc dependent scalar load per step)
    const unsigned long long actmask =
        __ballot((l < Ss) && (act[b * Ss + l] != 0));

    float4v h_d[16];
    #pragma unroll
    for (int mi = 0; mi < 16; ++mi) h_d[mi] = (float4v)0.f;
    uint4 hB[8];
    #pragma unroll
    for (int kk = 0; kk < 8; ++kk) hB[kk] = make_uint4(0u, 0u, 0u, 0u);

    // lane-constant butterfly predicates
    const bool hiq = (q >> 1) != 0;             // keep parity
    const bool par = (((q >> 1) ^ q) & 1) != 0; // round-2 send select
    const int  abase = (sl << 9) + (q << 4);
    const int  swz   = (sl & 7) << 4;
    const float* kvrow = kv + ((long)b * Ee + e) * Dd;

    __syncthreads();   // Ut staged

    const char* lb = reinterpret_cast<const char*>(Ut);

    for (int s = 0; s < Ss; ++s) {
        if ((actmask >> s) & 1ull) {
            const long bs = (long)b * Ss + s;
            const float gk_s = gk[bs * Ee + e];
            const float* erow = enc + bs * Dd;

            // ---- g-dot: dot(es, h[e]) — 4 independent partial chains ----
            float gd0 = 0.f, gd1 = 0.f, gd2 = 0.f, gd3 = 0.f;
            #pragma unroll
            for (int mi = 0; mi < 16; ++mi) {
                const float4 ev = *reinterpret_cast<const float4*>(erow + mi * 16 + q * 4);
                gd0 += ev.x * h_d[mi][0];
                gd1 += ev.y * h_d[mi][1];
                gd2 += ev.z * h_d[mi][2];
                gd3 += ev.w * h_d[mi][3];
            }
            float gd = (gd0 + gd1) + (gd2 + gd3);
            gd += __shfl_xor(gd, 16);
            gd += __shfl_xor(gd, 32);
            const float g = 1.f / (1.f + expf(-(gd + gk_s)));

            // ---- GEMM + epilogue in two mi-halves; A-frags double-buffered ----
            const float* ewrow = eWm + bs * Dd;
            float ss0 = 0.f, ss1 = 0.f, ss2 = 0.f, ss3 = 0.f;
            #pragma unroll
            for (int hf = 0; hf < 2; ++hf) {
                const char* lbh = lb + hf * (8 * 8192);
                float4v acc[8];
                #pragma unroll
                for (int m8 = 0; m8 < 8; ++m8) acc[m8] = (float4v)0.f;

                short8v A0[8], A1[8];
                // prefetch kk=0
                {
                    const int bk = abase ^ swz;
                    #pragma unroll
                    for (int m8 = 0; m8 < 8; ++m8)
                        A0[m8] = *reinterpret_cast<const short8v*>(lbh + bk + m8 * 8192);
                }
                #pragma unroll
                for (int kp = 0; kp < 4; ++kp) {
                    const int kkA = 2 * kp, kkB = 2 * kp + 1;
                    {   // prefetch kkB while computing kkA
                        const int bk = (abase + (kkB << 6)) ^ swz;
                        #pragma unroll
                        for (int m8 = 0; m8 < 8; ++m8)
                            A1[m8] = *reinterpret_cast<const short8v*>(lbh + bk + m8 * 8192);
                    }
                    {
                        const short8v bv = __builtin_bit_cast(short8v, hB[kkA]);
                        #pragma unroll
                        for (int m8 = 0; m8 < 8; ++m8)
                            acc[m8] = __builtin_amdgcn_mfma_f32_16x16x32_bf16(
                                A0[m8], bv, acc[m8], 0, 0, 0);
                    }
                    if (kp < 3) {   // prefetch next kkA while computing kkB
                        const int bk = (abase + ((kkB + 1) << 6)) ^ swz;
                        #pragma unroll
                        for (int m8 = 0; m8 < 8; ++m8)
                            A0[m8] = *reinterpret_cast<const short8v*>(lbh + bk + m8 * 8192);
                    }
                    {
                        const short8v bv = __builtin_bit_cast(short8v, hB[kkB]);
                        #pragma unroll
                        for (int m8 = 0; m8 < 8; ++m8)
                            acc[m8] = __builtin_amdgcn_mfma_f32_16x16x32_bf16(
                                A1[m8], bv, acc[m8], 0, 0, 0);
                    }
                }

                // epilogue half: issue all loads first, then math
                float4 kvv[8], eww[8];
                #pragma unroll
                for (int m8 = 0; m8 < 8; ++m8) {
                    const int mi = hf * 8 + m8;
                    kvv[m8] = *reinterpret_cast<const float4*>(kvrow + mi * 16 + q * 4);
                    eww[m8] = *reinterpret_cast<const float4*>(ewrow + mi * 16 + q * 4);
                }
                #pragma unroll
                for (int m8 = 0; m8 < 8; ++m8) {
                    const int mi = hf * 8 + m8;
                    const float kva[4] = {kvv[m8].x, kvv[m8].y, kvv[m8].z, kvv[m8].w};
                    const float ewa[4] = {eww[m8].x, eww[m8].y, eww[m8].z, eww[m8].w};
                    float hn0 = h_d[mi][0] + g * fmaxf(acc[m8][0] + kva[0] + ewa[0], 0.f);
                    float hn1 = h_d[mi][1] + g * fmaxf(acc[m8][1] + kva[1] + ewa[1], 0.f);
                    float hn2 = h_d[mi][2] + g * fmaxf(acc[m8][2] + kva[2] + ewa[2], 0.f);
                    float hn3 = h_d[mi][3] + g * fmaxf(acc[m8][3] + kva[3] + ewa[3], 0.f);
                    h_d[mi][0] = hn0; h_d[mi][1] = hn1;
                    h_d[mi][2] = hn2; h_d[mi][3] = hn3;
                    ss0 += hn0 * hn0; ss1 += hn1 * hn1;
                    ss2 += hn2 * hn2; ss3 += hn3 * hn3;
                }
            }
            float ss = (ss0 + ss1) + (ss2 + ss3);
            ss += __shfl_xor(ss, 16);
            ss += __shfl_xor(ss, 32);
            const float rn = rsqrtf(fmaxf(ss, 1e-12f));

            #pragma unroll
            for (int mi = 0; mi < 16; ++mi) {
                #pragma unroll
                for (int j = 0; j < 4; ++j) h_d[mi][j] *= rn;
            }
            // ---- rebuild bf16 B-frags: 2-round q-butterfly (xor32 then xor16) ----
            #pragma unroll
            for (int kk = 0; kk < 8; ++kk) {
                const unsigned int P0a = pk2(h_d[2 * kk][0],     h_d[2 * kk][1]);
                const unsigned int P0b = pk2(h_d[2 * kk][2],     h_d[2 * kk][3]);
                const unsigned int P1a = pk2(h_d[2 * kk + 1][0], h_d[2 * kk + 1][1]);
                const unsigned int P1b = pk2(h_d[2 * kk + 1][2], h_d[2 * kk + 1][3]);
                const unsigned int Ka  = hiq ? P1a : P0a, Kb  = hiq ? P1b : P0b;
                const unsigned int S1a = hiq ? P0a : P1a, S1b = hiq ? P0b : P1b;
                const unsigned int R1a = (unsigned int)__shfl_xor((int)S1a, 32);
                const unsigned int R1b = (unsigned int)__shfl_xor((int)S1b, 32);
                const unsigned int S2a = par ? Ka : R1a, S2b = par ? Kb : R1b;
                const unsigned int R2a = (unsigned int)__shfl_xor((int)S2a, 16);
                const unsigned int R2b = (unsigned int)__shfl_xor((int)S2b, 16);
                const unsigned int LOa = (q == 0) ? Ka : (q == 2) ? R1a : R2a;
                const unsigned int LOb = (q == 0) ? Kb : (q == 2) ? R1b : R2b;
                const unsigned int HIa = (q == 3) ? Ka : (q == 1) ? R1a : R2a;
                const unsigned int HIb = (q == 3) ? Kb : (q == 1) ? R1b : R2b;
                hB[kk] = make_uint4(LOa, LOb, HIa, HIb);
            }
        }
    }

    // ---- write back h (fp32) ----
    float* orow = out + ((long)b * Ee + e) * Dd;
    #pragma unroll
    for (int mi = 0; mi < 16; ++mi) {
        *reinterpret_cast<float4v*>(orow + mi * 16 + q * 4) = h_d[mi];
    }
}

extern "C" void kernel_launch(void* const* d_in, const int* in_sizes, int n_in,
                              void* d_out, int out_size, void* d_ws, size_t ws_size,
                              hipStream_t stream) {
    const int*   tok  = (const int*)d_in[0];    // (B,S,L) int32
    const float* mask = (const float*)d_in[1];  // (B,S,L) f32
    const float* keys = (const float*)d_in[2];  // (B,E,D) f32
    const float* emb  = (const float*)d_in[3];  // (VOCAB,D) f32
    const float* U    = (const float*)d_in[4];  // (D,D)
    const float* V    = (const float*)d_in[5];  // (D,D)
    const float* W    = (const float*)d_in[6];  // (D,D)
    float* out = (float*)d_out;

    // workspace layout (floats)
    float* enc = (float*)d_ws;                    // B*S*D      = 2,097,152
    float* kv  = enc + (long)Bb * Ss * Dd;        // B*E*D      = 4,194,304
    float* eW  = kv  + (long)Bb * Ee * Dd;        // B*S*D      = 2,097,152
    float* gkv = eW  + (long)Bb * Ss * Dd;        // B*S*E      =   524,288
    int*   act = (int*)(gkv + (long)Bb * Ss * Ee);// B*S        =     8,192 ints
    unsigned short* Utg = (unsigned short*)(act + Bb * Ss);  // D*D bf16 = 131,072 B

    k_enc<<<Bb * Ss, Dd, 0, stream>>>(tok, mask, emb, enc, act);
    k_rowmat<<<(Bb * Ee) / 64, 256, 0, stream>>>(keys, V, kv);   // kv = keys @ V
    k_rowmat<<<(Bb * Ss) / 64, 256, 0, stream>>>(enc, W, eW);    // eW = enc @ W
    k_gk<<<Bb * Ss, 256, 0, stream>>>(enc, keys, gkv);           // gk = dot(enc, keys)
    k_ut<<<Dd / 16, Dd, 0, stream>>>(U, Utg);                    // Utg = bf16(U^T)
    k_scan<<<Bb, 256, 0, stream>>>(enc, act, gkv, kv, eW, Utg, out);
}

// Round 7
// 460.409 us; speedup vs baseline: 2.6221x; 1.0712x over previous
//
#include <hip/hip_runtime.h>
#include <hip/hip_bf16.h>

// Problem constants (StaticRecurrentEntNet): B=256,S=32,L=32,D=256,E=64,VOCAB=50000
#define Bb 256
#define Ss 32
#define Ll 32
#define Dd 256
#define Ee 64

typedef __attribute__((ext_vector_type(8))) short short8v;
typedef __attribute__((ext_vector_type(4))) float float4v;

static __device__ __forceinline__ unsigned short f2bf(float f) {
    unsigned int x = __float_as_uint(f);
    return (unsigned short)((x + 0x7fffu + ((x >> 16) & 1u)) >> 16);   // RNE
}
static __device__ __forceinline__ unsigned int pk2(float a, float b) {
    return (unsigned int)f2bf(a) | ((unsigned int)f2bf(b) << 16);
}

// ---------------- Kernel A: enc[bs][d] = sum_l emb[tok[bs][l]][d]*mask[bs][l]; active[bs]
__global__ void k_enc(const int* __restrict__ tok, const float* __restrict__ mask,
                      const float* __restrict__ emb, float* __restrict__ enc,
                      int* __restrict__ act) {
    int bs = blockIdx.x;            // 0..B*S-1
    int d  = threadIdx.x;           // 0..255
    const int*   t = tok  + (long)bs * Ll;
    const float* m = mask + (long)bs * Ll;
    float acc = 0.f;
    #pragma unroll 4
    for (int l = 0; l < Ll; ++l) {
        acc += emb[(long)t[l] * Dd + d] * m[l];
    }
    enc[(long)bs * Dd + d] = acc;
    if (d == 0) {
        float s = 0.f;
        for (int l = 0; l < Ll; ++l) s += m[l];
        act[bs] = (s > 0.f) ? 1 : 0;
    }
}

// ---------------- Kernel B: Y[rows][256] = X[rows][256] @ M[256][256]  (fp32)
// 16 rows per block (round-2-proven variant).
__global__ void k_rowmat(const float* __restrict__ X, const float* __restrict__ M,
                         float* __restrict__ Y) {
    __shared__ __align__(16) float xs[16 * Dd];
    int tid = threadIdx.x;
    long row0 = (long)blockIdx.x * 16;
    #pragma unroll
    for (int i = 0; i < 16; ++i) xs[i * Dd + tid] = X[(row0 + i) * Dd + tid];
    __syncthreads();
    int cg = tid & 63;   // cols cg*4 .. +3
    int rq = tid >> 6;   // rows rq*4 .. +3
    float acc[4][4];
    #pragma unroll
    for (int r = 0; r < 4; ++r)
        #pragma unroll
        for (int c = 0; c < 4; ++c) acc[r][c] = 0.f;
    for (int d = 0; d < Dd; ++d) {
        float4 mv = *reinterpret_cast<const float4*>(&M[d * Dd + cg * 4]);
        #pragma unroll
        for (int r = 0; r < 4; ++r) {
            float x = xs[(rq * 4 + r) * Dd + d];
            acc[r][0] += x * mv.x; acc[r][1] += x * mv.y;
            acc[r][2] += x * mv.z; acc[r][3] += x * mv.w;
        }
    }
    #pragma unroll
    for (int r = 0; r < 4; ++r) {
        float4 o = make_float4(acc[r][0], acc[r][1], acc[r][2], acc[r][3]);
        *reinterpret_cast<float4*>(&Y[(row0 + rq * 4 + r) * Dd + cg * 4]) = o;
    }
}

// ---------------- Kernel Bgk v2: gk[b*32+s][e] = dot(enc[b][s], keys[b][e])
// One block per b. keys_b staged once in swizzled LDS (reused by all 32 s).
__global__ __launch_bounds__(256) void k_gk(const float* __restrict__ enc,
                                            const float* __restrict__ keys,
                                            float* __restrict__ gk) {
    __shared__ __align__(16) char kls[Ee * 1024];      // keys_b bf-free fp32, swizzled, 64KB
    __shared__ __align__(16) float es[Ss * Dd];        // enc_b, 32KB
    const int tid = threadIdx.x;
    const int b   = blockIdx.x;
    // stage keys[b] (64 rows x 256 f32) swizzled: byte = e*1024 + d4*16 ^ ((e&7)<<4)
    {
        const float4* kg = reinterpret_cast<const float4*>(keys + (long)b * Ee * Dd);
        #pragma unroll
        for (int i = 0; i < 16; ++i) {
            const int idx = tid + 256 * i;             // f4 unit, 0..4095
            const int e   = idx >> 6;
            const int d4  = idx & 63;
            *reinterpret_cast<float4*>(kls + (((e << 10) + (d4 << 4)) ^ ((e & 7) << 4)))
                = kg[idx];
        }
        const float4* eg = reinterpret_cast<const float4*>(enc + (long)b * Ss * Dd);
        float4* es4 = reinterpret_cast<float4*>(es);
        #pragma unroll
        for (int i = 0; i < 8; ++i) es4[tid + 256 * i] = eg[tid + 256 * i];
    }
    __syncthreads();
    const int w = tid >> 6;        // wave: s in [w*8, w*8+8)
    const int e = tid & 63;
    float acc[8];
    #pragma unroll
    for (int i = 0; i < 8; ++i) acc[i] = 0.f;
    const char* krow = kls;        // lane's row e with swizzle applied per read
    for (int d4 = 0; d4 < 64; ++d4) {
        const float4 kvf = *reinterpret_cast<const float4*>(
            krow + (((e << 10) + (d4 << 4)) ^ ((e & 7) << 4)));
        #pragma unroll
        for (int i = 0; i < 8; ++i) {
            const float4 ev = *reinterpret_cast<const float4*>(&es[(w * 8 + i) * Dd + d4 * 4]);
            acc[i] += ev.x * kvf.x + ev.y * kvf.y + ev.z * kvf.z + ev.w * kvf.w;
        }
    }
    #pragma unroll
    for (int i = 0; i < 8; ++i)
        gk[((long)b * Ss + w * 8 + i) * Ee + e] = acc[i];
}

// ---------------- Kernel Ut: Utg[c][k] = bf16(U[k][c])  (pre-transpose for A-operand)
__global__ void k_ut(const float* __restrict__ U, unsigned short* __restrict__ Utg) {
    const int c0 = blockIdx.x * 16;
    const int k  = threadIdx.x;      // 0..255
    float v[16];
    #pragma unroll
    for (int i = 0; i < 16; ++i) v[i] = U[k * Dd + c0 + i];
    #pragma unroll
    for (int i = 0; i < 16; ++i) Utg[(c0 + i) * Dd + k] = f2bf(v[i]);
}

// ---------------- Kernel D v3: 32-step recurrence.
// 512 threads = 8 waves; wave w owns OUTPUT dims c in [w*32, w*32+32) for ALL 64
// entities. A = U^T slice in REGISTERS (64 VGPR, zero LDS traffic for U).
// B = h from a single 32KB swizzled bf16 LDS mirror hbf[e][k] (rewritten each step).
// D-layout: col=lane&15 = e-within-tile, row=4q+j = c-within-tile.
// 2 barriers/step: B1 publishes {hbf(s), part_g(s)}; B2 publishes part_rn(s).
// Race-freedom: hbf writes are post-B2 (all GEMM reads done); part_g(s+1) writes
// are post-B2(s) (all g-reads done); part_rn(s+1) writes are post-B1(s+1).
__global__ __launch_bounds__(512, 1) void k_scan(
    const float* __restrict__ enc, const int* __restrict__ act,
    const float* __restrict__ gk,  const float* __restrict__ kv,
    const float* __restrict__ eWm, const unsigned short* __restrict__ Utg,
    float* __restrict__ out) {
    __shared__ __align__(16) unsigned short hbf[Ee * Dd];  // [e][k] bf16, swizzled, 32KB
    __shared__ float part_g[8][Ee];
    __shared__ float part_rn[8][Ee];

    const int tid = threadIdx.x;
    const int b   = blockIdx.x;
    const int w   = tid >> 6;       // wave id 0..7, c0 = w*32
    const int l   = tid & 63;
    const int q   = l >> 4;
    const int sl  = l & 15;
    const int c0  = w * 32;

    // ---- zero hbf + parts ----
    {
        uint4 z4 = make_uint4(0u, 0u, 0u, 0u);
        uint4* hz = reinterpret_cast<uint4*>(hbf);
        #pragma unroll
        for (int i = 0; i < 4; ++i) hz[tid + 512 * i] = z4;
        (&part_g[0][0])[tid]  = 0.f;
        (&part_rn[0][0])[tid] = 0.f;
    }

    // ---- A-frags: U^T slice, registers for the whole kernel (64 VGPR) ----
    short8v aU[2][8];
    #pragma unroll
    for (int mi = 0; mi < 2; ++mi)
        #pragma unroll
        for (int kk = 0; kk < 8; ++kk)
            aU[mi][kk] = *reinterpret_cast<const short8v*>(
                Utg + (c0 + mi * 16 + sl) * Dd + kk * 32 + q * 8);

    // ---- kv preload (loop-invariant): kvr[mi][n] (32 VGPR) ----
    float4v kvr[2][4];
    #pragma unroll
    for (int mi = 0; mi < 2; ++mi)
        #pragma unroll
        for (int n = 0; n < 4; ++n)
            kvr[mi][n] = *reinterpret_cast<const float4v*>(
                kv + ((long)b * Ee + n * 16 + sl) * Dd + c0 + mi * 16 + q * 4);

    float4v h_d[2][4];   // h[e = n*16+sl][c = c0+mi*16+q*4+j]
    #pragma unroll
    for (int mi = 0; mi < 2; ++mi)
        #pragma unroll
        for (int n = 0; n < 4; ++n) h_d[mi][n] = (float4v)0.f;

    const unsigned long long actmask = __ballot((l < Ss) && (act[b * Ss + l] != 0));
    const int bswz = (sl & 7) << 4;
    char* hb = reinterpret_cast<char*>(hbf);

    // es prefetch chain (always advanced, so esc is fresh at every step)
    float4v esN[2];
    #pragma unroll
    for (int mi = 0; mi < 2; ++mi)
        esN[mi] = *reinterpret_cast<const float4v*>(
            enc + (long)(b * Ss) * Dd + c0 + mi * 16 + q * 4);

    __syncthreads();   // hbf/part zero visible

    for (int s = 0; s < Ss; ++s) {
        const long bs = (long)b * Ss + s;
        float4v esc[2] = {esN[0], esN[1]};
        if (s + 1 < Ss) {
            #pragma unroll
            for (int mi = 0; mi < 2; ++mi)
                esN[mi] = *reinterpret_cast<const float4v*>(
                    enc + (bs + 1) * Dd + c0 + mi * 16 + q * 4);
        }
        if ((actmask >> s) & 1ull) {
            // gk loads (consumed after B1 — latency hidden)
            float gkl[4];
            #pragma unroll
            for (int n = 0; n < 4; ++n) gkl[n] = gk[bs * Ee + n * 16 + sl];

            // ---- g-partials over this wave's 32 c, all 64 e ----
            #pragma unroll
            for (int n = 0; n < 4; ++n) {
                float pg = esc[0][0] * h_d[0][n][0] + esc[0][1] * h_d[0][n][1]
                         + esc[0][2] * h_d[0][n][2] + esc[0][3] * h_d[0][n][3]
                         + esc[1][0] * h_d[1][n][0] + esc[1][1] * h_d[1][n][1]
                         + esc[1][2] * h_d[1][n][2] + esc[1][3] * h_d[1][n][3];
                pg += __shfl_xor(pg, 16);
                pg += __shfl_xor(pg, 32);
                if (q == 0) part_g[w][n * 16 + sl] = pg;
            }
            __syncthreads();                                   // B1

            // ---- g-final (overlaps GEMM issue; independent chains) ----
            float g4[4];
            #pragma unroll
            for (int n = 0; n < 4; ++n) {
                const int e = n * 16 + sl;
                float x = part_g[0][e] + part_g[1][e] + part_g[2][e] + part_g[3][e]
                        + part_g[4][e] + part_g[5][e] + part_g[6][e] + part_g[7][e]
                        + gkl[n];
                g4[n] = 1.f / (1.f + expf(-x));
            }

            // ---- GEMM: acc[mi][n] = U^T-slice @ h^T  (A regs, B from hbf) ----
            float4v acc[2][4];
            #pragma unroll
            for (int mi = 0; mi < 2; ++mi)
                #pragma unroll
                for (int n = 0; n < 4; ++n) acc[mi][n] = (float4v)0.f;
            #pragma unroll
            for (int kk = 0; kk < 8; ++kk) {
                short8v bh[4];
                #pragma unroll
                for (int n = 0; n < 4; ++n)
                    bh[n] = *reinterpret_cast<const short8v*>(
                        hb + ((((n * 16 + sl) << 9) + (kk << 6) + (q << 4)) ^ bswz));
                #pragma unroll
                for (int mi = 0; mi < 2; ++mi)
                    #pragma unroll
                    for (int n = 0; n < 4; ++n)
                        acc[mi][n] = __builtin_amdgcn_mfma_f32_16x16x32_bf16(
                            aU[mi][kk], bh[n], acc[mi][n], 0, 0, 0);
            }

            // ---- epilogue: h_t = relu(acc+kv+eW); h_d += g*h_t; ss partials ----
            const float* ewrow = eWm + bs * Dd + c0;
            float ssp[4];
            #pragma unroll
            for (int n = 0; n < 4; ++n) {
                float sp = 0.f;
                #pragma unroll
                for (int mi = 0; mi < 2; ++mi) {
                    const float4v ew = *reinterpret_cast<const float4v*>(
                        ewrow + mi * 16 + q * 4);
                    #pragma unroll
                    for (int j = 0; j < 4; ++j) {
                        float ht = acc[mi][n][j] + kvr[mi][n][j] + ew[j];
                        ht = fmaxf(ht, 0.f);
                        const float hn = h_d[mi][n][j] + g4[n] * ht;
                        h_d[mi][n][j] = hn;
                        sp += hn * hn;
                    }
                }
                ssp[n] = sp;
            }
            #pragma unroll
            for (int n = 0; n < 4; ++n) {
                ssp[n] += __shfl_xor(ssp[n], 16);
                ssp[n] += __shfl_xor(ssp[n], 32);
                if (q == 0) part_rn[w][n * 16 + sl] = ssp[n];
            }
            __syncthreads();                                   // B2

            // ---- normalize + refresh bf16 mirror ----
            #pragma unroll
            for (int n = 0; n < 4; ++n) {
                const int e = n * 16 + sl;
                const float t = part_rn[0][e] + part_rn[1][e] + part_rn[2][e]
                              + part_rn[3][e] + part_rn[4][e] + part_rn[5][e]
                              + part_rn[6][e] + part_rn[7][e];
                const float rn = rsqrtf(fmaxf(t, 1e-12f));
                #pragma unroll
                for (int mi = 0; mi < 2; ++mi) {
                    h_d[mi][n][0] *= rn; h_d[mi][n][1] *= rn;
                    h_d[mi][n][2] *= rn; h_d[mi][n][3] *= rn;
                    const int c = c0 + mi * 16 + q * 4;
                    const unsigned int u0 = pk2(h_d[mi][n][0], h_d[mi][n][1]);
                    const unsigned int u1 = pk2(h_d[mi][n][2], h_d[mi][n][3]);
                    *reinterpret_cast<uint2*>(hb + (((e << 9) + (c << 1)) ^ bswz))
                        = make_uint2(u0, u1);
                }
            }
        }
    }

    // ---- write back h (fp32) ----
    #pragma unroll
    for (int mi = 0; mi < 2; ++mi)
        #pragma unroll
        for (int n = 0; n < 4; ++n)
            *reinterpret_cast<float4v*>(
                out + ((long)b * Ee + n * 16 + sl) * Dd + c0 + mi * 16 + q * 4)
                = h_d[mi][n];
}

extern "C" void kernel_launch(void* const* d_in, const int* in_sizes, int n_in,
                              void* d_out, int out_size, void* d_ws, size_t ws_size,
                              hipStream_t stream) {
    const int*   tok  = (const int*)d_in[0];    // (B,S,L) int32
    const float* mask = (const float*)d_in[1];  // (B,S,L) f32
    const float* keys = (const float*)d_in[2];  // (B,E,D) f32
    const float* emb  = (const float*)d_in[3];  // (VOCAB,D) f32
    const float* U    = (const float*)d_in[4];  // (D,D)
    const float* V    = (const float*)d_in[5];  // (D,D)
    const float* W    = (const float*)d_in[6];  // (D,D)
    float* out = (float*)d_out;

    // workspace layout (floats)
    float* enc = (float*)d_ws;                    // B*S*D      = 2,097,152
    float* kv  = enc + (long)Bb * Ss * Dd;        // B*E*D      = 4,194,304
    float* eW  = kv  + (long)Bb * Ee * Dd;        // B*S*D      = 2,097,152
    float* gkv = eW  + (long)Bb * Ss * Dd;        // B*S*E      =   524,288
    int*   act = (int*)(gkv + (long)Bb * Ss * Ee);// B*S        =     8,192 ints
    unsigned short* Utg = (unsigned short*)(act + Bb * Ss);  // D*D bf16 = 131,072 B

    k_enc<<<Bb * Ss, Dd, 0, stream>>>(tok, mask, emb, enc, act);
    k_rowmat<<<(Bb * Ee) / 16, 256, 0, stream>>>(keys, V, kv);   // kv = keys @ V
    k_rowmat<<<(Bb * Ss) / 16, 256, 0, stream>>>(enc, W, eW);    // eW = enc @ W
    k_gk<<<Bb, 256, 0, stream>>>(enc, keys, gkv);                // gk = dot(enc, keys)
    k_ut<<<Dd / 16, Dd, 0, stream>>>(U, Utg);                    // Utg = bf16(U^T)
    k_scan<<<Bb, 512, 0, stream>>>(enc, act, gkv, kv, eW, Utg, out);
}

// Round 9
// 452.827 us; speedup vs baseline: 2.6660x; 1.0167x over previous
//
#include <hip/hip_runtime.h>
#include <hip/hip_bf16.h>

// Problem constants (StaticRecurrentEntNet): B=256,S=32,L=32,D=256,E=64,VOCAB=50000
#define Bb 256
#define Ss 32
#define Ll 32
#define Dd 256
#define Ee 64

typedef __attribute__((ext_vector_type(8))) short short8v;
typedef __attribute__((ext_vector_type(4))) float float4v;

static __device__ __forceinline__ unsigned short f2bf(float f) {
    unsigned int x = __float_as_uint(f);
    return (unsigned short)((x + 0x7fffu + ((x >> 16) & 1u)) >> 16);   // RNE
}
static __device__ __forceinline__ unsigned int pk2(float a, float b) {
    return (unsigned int)f2bf(a) | ((unsigned int)f2bf(b) << 16);
}

// ---------------- Kernel A: enc[bs][d] = sum_l emb[tok[bs][l]][d]*mask[bs][l]; active[bs]
__global__ void k_enc(const int* __restrict__ tok, const float* __restrict__ mask,
                      const float* __restrict__ emb, float* __restrict__ enc,
                      int* __restrict__ act) {
    int bs = blockIdx.x;            // 0..B*S-1
    int d  = threadIdx.x;           // 0..255
    const int*   t = tok  + (long)bs * Ll;
    const float* m = mask + (long)bs * Ll;
    float acc = 0.f;
    #pragma unroll 4
    for (int l = 0; l < Ll; ++l) {
        acc += emb[(long)t[l] * Dd + d] * m[l];
    }
    enc[(long)bs * Dd + d] = acc;
    if (d == 0) {
        float s = 0.f;
        for (int l = 0; l < Ll; ++l) s += m[l];
        act[bs] = (s > 0.f) ? 1 : 0;
    }
}

// ---------------- Kernel B: Y[rows][256] = X[rows][256] @ M[256][256]  (fp32)
// 16 rows per block (round-2-proven variant).
__global__ void k_rowmat(const float* __restrict__ X, const float* __restrict__ M,
                         float* __restrict__ Y) {
    __shared__ __align__(16) float xs[16 * Dd];
    int tid = threadIdx.x;
    long row0 = (long)blockIdx.x * 16;
    #pragma unroll
    for (int i = 0; i < 16; ++i) xs[i * Dd + tid] = X[(row0 + i) * Dd + tid];
    __syncthreads();
    int cg = tid & 63;   // cols cg*4 .. +3
    int rq = tid >> 6;   // rows rq*4 .. +3
    float acc[4][4];
    #pragma unroll
    for (int r = 0; r < 4; ++r)
        #pragma unroll
        for (int c = 0; c < 4; ++c) acc[r][c] = 0.f;
    for (int d = 0; d < Dd; ++d) {
        float4 mv = *reinterpret_cast<const float4*>(&M[d * Dd + cg * 4]);
        #pragma unroll
        for (int r = 0; r < 4; ++r) {
            float x = xs[(rq * 4 + r) * Dd + d];
            acc[r][0] += x * mv.x; acc[r][1] += x * mv.y;
            acc[r][2] += x * mv.z; acc[r][3] += x * mv.w;
        }
    }
    #pragma unroll
    for (int r = 0; r < 4; ++r) {
        float4 o = make_float4(acc[r][0], acc[r][1], acc[r][2], acc[r][3]);
        *reinterpret_cast<float4*>(&Y[(row0 + rq * 4 + r) * Dd + cg * 4]) = o;
    }
}

// ---------------- Kernel Bgk v2: gk[b*32+s][e] = dot(enc[b][s], keys[b][e])
// One block per b. keys_b staged once in swizzled LDS (reused by all 32 s).
__global__ __launch_bounds__(256) void k_gk(const float* __restrict__ enc,
                                            const float* __restrict__ keys,
                                            float* __restrict__ gk) {
    __shared__ __align__(16) char kls[Ee * 1024];      // keys_b fp32, swizzled, 64KB
    __shared__ __align__(16) float es[Ss * Dd];        // enc_b, 32KB
    const int tid = threadIdx.x;
    const int b   = blockIdx.x;
    {
        const float4* kg = reinterpret_cast<const float4*>(keys + (long)b * Ee * Dd);
        #pragma unroll
        for (int i = 0; i < 16; ++i) {
            const int idx = tid + 256 * i;             // f4 unit, 0..4095
            const int e   = idx >> 6;
            const int d4  = idx & 63;
            *reinterpret_cast<float4*>(kls + (((e << 10) + (d4 << 4)) ^ ((e & 7) << 4)))
                = kg[idx];
        }
        const float4* eg = reinterpret_cast<const float4*>(enc + (long)b * Ss * Dd);
        float4* es4 = reinterpret_cast<float4*>(es);
        #pragma unroll
        for (int i = 0; i < 8; ++i) es4[tid + 256 * i] = eg[tid + 256 * i];
    }
    __syncthreads();
    const int w = tid >> 6;        // wave: s in [w*8, w*8+8)
    const int e = tid & 63;
    float acc[8];
    #pragma unroll
    for (int i = 0; i < 8; ++i) acc[i] = 0.f;
    const char* krow = kls;
    for (int d4 = 0; d4 < 64; ++d4) {
        const float4 kvf = *reinterpret_cast<const float4*>(
            krow + (((e << 10) + (d4 << 4)) ^ ((e & 7) << 4)));
        #pragma unroll
        for (int i = 0; i < 8; ++i) {
            const float4 ev = *reinterpret_cast<const float4*>(&es[(w * 8 + i) * Dd + d4 * 4]);
            acc[i] += ev.x * kvf.x + ev.y * kvf.y + ev.z * kvf.z + ev.w * kvf.w;
        }
    }
    #pragma unroll
    for (int i = 0; i < 8; ++i)
        gk[((long)b * Ss + w * 8 + i) * Ee + e] = acc[i];
}

// ---------------- Kernel Ut: Utg[c][k] = bf16(U[k][c])  (pre-transpose for A-operand)
__global__ void k_ut(const float* __restrict__ U, unsigned short* __restrict__ Utg) {
    const int c0 = blockIdx.x * 16;
    const int k  = threadIdx.x;      // 0..255
    float v[16];
    #pragma unroll
    for (int i = 0; i < 16; ++i) v[i] = U[k * Dd + c0 + i];
    #pragma unroll
    for (int i = 0; i < 16; ++i) Utg[(c0 + i) * Dd + k] = f2bf(v[i]);
}

// ---------------- Kernel D v3.1: 32-step recurrence.
// 512 threads = 8 waves; wave w owns OUTPUT dims c in [w*32, w*32+32) for ALL 64
// entities. A = U^T slice in REGISTERS (64 VGPR); B = h from 32KB swizzled bf16
// LDS mirror. Round-8 fix: round 7's __launch_bounds__(512,1) let the compiler
// cap VGPR at 128 (4 waves/EU heuristic) -> 71MB/dispatch scratch spill
// (WRITE_SIZE 88MB). Pin EXACTLY 2 waves/EU -> 256-VGPR budget, demand ~220, no
// spill. 1 block/CU resident (grid 256 = CU count).
__global__ __attribute__((amdgpu_flat_work_group_size(512, 512),
                          amdgpu_waves_per_eu(2, 2))) void k_scan(
    const float* __restrict__ enc, const int* __restrict__ act,
    const float* __restrict__ gk,  const float* __restrict__ kv,
    const float* __restrict__ eWm, const unsigned short* __restrict__ Utg,
    float* __restrict__ out) {
    __shared__ __align__(16) unsigned short hbf[Ee * Dd];  // [e][k] bf16, swizzled, 32KB
    __shared__ float part_g[8][Ee];
    __shared__ float part_rn[8][Ee];

    const int tid = threadIdx.x;
    const int b   = blockIdx.x;
    const int w   = tid >> 6;       // wave id 0..7, c0 = w*32
    const int l   = tid & 63;
    const int q   = l >> 4;
    const int sl  = l & 15;
    const int c0  = w * 32;

    // ---- zero hbf + parts ----
    {
        uint4 z4 = make_uint4(0u, 0u, 0u, 0u);
        uint4* hz = reinterpret_cast<uint4*>(hbf);
        #pragma unroll
        for (int i = 0; i < 4; ++i) hz[tid + 512 * i] = z4;
        (&part_g[0][0])[tid]  = 0.f;
        (&part_rn[0][0])[tid] = 0.f;
    }

    // ---- A-frags: U^T slice, registers for the whole kernel (64 VGPR) ----
    short8v aU[2][8];
    #pragma unroll
    for (int mi = 0; mi < 2; ++mi)
        #pragma unroll
        for (int kk = 0; kk < 8; ++kk)
            aU[mi][kk] = *reinterpret_cast<const short8v*>(
                Utg + (c0 + mi * 16 + sl) * Dd + kk * 32 + q * 8);

    // ---- kv preload (loop-invariant): kvr[mi][n] (32 VGPR) ----
    float4v kvr[2][4];
    #pragma unroll
    for (int mi = 0; mi < 2; ++mi)
        #pragma unroll
        for (int n = 0; n < 4; ++n)
            kvr[mi][n] = *reinterpret_cast<const float4v*>(
                kv + ((long)b * Ee + n * 16 + sl) * Dd + c0 + mi * 16 + q * 4);

    float4v h_d[2][4];   // h[e = n*16+sl][c = c0+mi*16+q*4+j]
    #pragma unroll
    for (int mi = 0; mi < 2; ++mi)
        #pragma unroll
        for (int n = 0; n < 4; ++n) h_d[mi][n] = (float4v)0.f;

    const unsigned long long actmask = __ballot((l < Ss) && (act[b * Ss + l] != 0));
    const int bswz = (sl & 7) << 4;
    char* hb = reinterpret_cast<char*>(hbf);

    // es prefetch chain (always advanced, so esc is fresh at every step)
    float4v esN[2];
    #pragma unroll
    for (int mi = 0; mi < 2; ++mi)
        esN[mi] = *reinterpret_cast<const float4v*>(
            enc + (long)(b * Ss) * Dd + c0 + mi * 16 + q * 4);

    __syncthreads();   // hbf/part zero visible

    for (int s = 0; s < Ss; ++s) {
        const long bs = (long)b * Ss + s;
        float4v esc[2] = {esN[0], esN[1]};
        if (s + 1 < Ss) {
            #pragma unroll
            for (int mi = 0; mi < 2; ++mi)
                esN[mi] = *reinterpret_cast<const float4v*>(
                    enc + (bs + 1) * Dd + c0 + mi * 16 + q * 4);
        }
        if ((actmask >> s) & 1ull) {
            // gk loads (consumed after B1 — latency hidden)
            float gkl[4];
            #pragma unroll
            for (int n = 0; n < 4; ++n) gkl[n] = gk[bs * Ee + n * 16 + sl];

            // ---- g-partials over this wave's 32 c, all 64 e ----
            #pragma unroll
            for (int n = 0; n < 4; ++n) {
                float pg = esc[0][0] * h_d[0][n][0] + esc[0][1] * h_d[0][n][1]
                         + esc[0][2] * h_d[0][n][2] + esc[0][3] * h_d[0][n][3]
                         + esc[1][0] * h_d[1][n][0] + esc[1][1] * h_d[1][n][1]
                         + esc[1][2] * h_d[1][n][2] + esc[1][3] * h_d[1][n][3];
                pg += __shfl_xor(pg, 16);
                pg += __shfl_xor(pg, 32);
                if (q == 0) part_g[w][n * 16 + sl] = pg;
            }
            __syncthreads();                                   // B1

            // ---- g-final (overlaps GEMM issue; independent chains) ----
            float g4[4];
            #pragma unroll
            for (int n = 0; n < 4; ++n) {
                const int e = n * 16 + sl;
                float x = part_g[0][e] + part_g[1][e] + part_g[2][e] + part_g[3][e]
                        + part_g[4][e] + part_g[5][e] + part_g[6][e] + part_g[7][e]
                        + gkl[n];
                g4[n] = 1.f / (1.f + expf(-x));
            }

            // ---- GEMM: acc[mi][n] = U^T-slice @ h^T  (A regs, B from hbf) ----
            float4v acc[2][4];
            #pragma unroll
            for (int mi = 0; mi < 2; ++mi)
                #pragma unroll
                for (int n = 0; n < 4; ++n) acc[mi][n] = (float4v)0.f;
            #pragma unroll
            for (int kk = 0; kk < 8; ++kk) {
                short8v bh[4];
                #pragma unroll
                for (int n = 0; n < 4; ++n)
                    bh[n] = *reinterpret_cast<const short8v*>(
                        hb + ((((n * 16 + sl) << 9) + (kk << 6) + (q << 4)) ^ bswz));
                #pragma unroll
                for (int mi = 0; mi < 2; ++mi)
                    #pragma unroll
                    for (int n = 0; n < 4; ++n)
                        acc[mi][n] = __builtin_amdgcn_mfma_f32_16x16x32_bf16(
                            aU[mi][kk], bh[n], acc[mi][n], 0, 0, 0);
            }

            // ---- epilogue: h_t = relu(acc+kv+eW); h_d += g*h_t; ss partials ----
            const float* ewrow = eWm + bs * Dd + c0;
            float ssp[4];
            #pragma unroll
            for (int n = 0; n < 4; ++n) {
                float sp = 0.f;
                #pragma unroll
                for (int mi = 0; mi < 2; ++mi) {
                    const float4v ew = *reinterpret_cast<const float4v*>(
                        ewrow + mi * 16 + q * 4);
                    #pragma unroll
                    for (int j = 0; j < 4; ++j) {
                        float ht = acc[mi][n][j] + kvr[mi][n][j] + ew[j];
                        ht = fmaxf(ht, 0.f);
                        const float hn = h_d[mi][n][j] + g4[n] * ht;
                        h_d[mi][n][j] = hn;
                        sp += hn * hn;
                    }
                }
                ssp[n] = sp;
            }
            #pragma unroll
            for (int n = 0; n < 4; ++n) {
                ssp[n] += __shfl_xor(ssp[n], 16);
                ssp[n] += __shfl_xor(ssp[n], 32);
                if (q == 0) part_rn[w][n * 16 + sl] = ssp[n];
            }
            __syncthreads();                                   // B2

            // ---- normalize + refresh bf16 mirror ----
            #pragma unroll
            for (int n = 0; n < 4; ++n) {
                const int e = n * 16 + sl;
                const float t = part_rn[0][e] + part_rn[1][e] + part_rn[2][e]
                              + part_rn[3][e] + part_rn[4][e] + part_rn[5][e]
                              + part_rn[6][e] + part_rn[7][e];
                const float rn = rsqrtf(fmaxf(t, 1e-12f));
                #pragma unroll
                for (int mi = 0; mi < 2; ++mi) {
                    h_d[mi][n][0] *= rn; h_d[mi][n][1] *= rn;
                    h_d[mi][n][2] *= rn; h_d[mi][n][3] *= rn;
                    const int c = c0 + mi * 16 + q * 4;
                    const unsigned int u0 = pk2(h_d[mi][n][0], h_d[mi][n][1]);
                    const unsigned int u1 = pk2(h_d[mi][n][2], h_d[mi][n][3]);
                    *reinterpret_cast<uint2*>(hb + (((e << 9) + (c << 1)) ^ bswz))
                        = make_uint2(u0, u1);
                }
            }
        }
    }

    // ---- write back h (fp32) ----
    #pragma unroll
    for (int mi = 0; mi < 2; ++mi)
        #pragma unroll
        for (int n = 0; n < 4; ++n)
            *reinterpret_cast<float4v*>(
                out + ((long)b * Ee + n * 16 + sl) * Dd + c0 + mi * 16 + q * 4)
                = h_d[mi][n];
}

extern "C" void kernel_launch(void* const* d_in, const int* in_sizes, int n_in,
                              void* d_out, int out_size, void* d_ws, size_t ws_size,
                              hipStream_t stream) {
    const int*   tok  = (const int*)d_in[0];    // (B,S,L) int32
    const float* mask = (const float*)d_in[1];  // (B,S,L) f32
    const float* keys = (const float*)d_in[2];  // (B,E,D) f32
    const float* emb  = (const float*)d_in[3];  // (VOCAB,D) f32
    const float* U    = (const float*)d_in[4];  // (D,D)
    const float* V    = (const float*)d_in[5];  // (D,D)
    const float* W    = (const float*)d_in[6];  // (D,D)
    float* out = (float*)d_out;

    // workspace layout (floats)
    float* enc = (float*)d_ws;                    // B*S*D      = 2,097,152
    float* kv  = enc + (long)Bb * Ss * Dd;        // B*E*D      = 4,194,304
    float* eW  = kv  + (long)Bb * Ee * Dd;        // B*S*D      = 2,097,152
    float* gkv = eW  + (long)Bb * Ss * Dd;        // B*S*E      =   524,288
    int*   act = (int*)(gkv + (long)Bb * Ss * Ee);// B*S        =     8,192 ints
    unsigned short* Utg = (unsigned short*)(act + Bb * Ss);  // D*D bf16 = 131,072 B

    k_enc<<<Bb * Ss, Dd, 0, stream>>>(tok, mask, emb, enc, act);
    k_rowmat<<<(Bb * Ee) / 16, 256, 0, stream>>>(keys, V, kv);   // kv = keys @ V
    k_rowmat<<<(Bb * Ss) / 16, 256, 0, stream>>>(enc, W, eW);    // eW = enc @ W
    k_gk<<<Bb, 256, 0, stream>>>(enc, keys, gkv);                // gk = dot(enc, keys)
    k_ut<<<Dd / 16, Dd, 0, stream>>>(U, Utg);                    // Utg = bf16(U^T)
    k_scan<<<Bb, 512, 0, stream>>>(enc, act, gkv, kv, eW, Utg, out);
}